// Round 4
// baseline (398.697 us; speedup 1.0000x reference)
//
#include <hip/hip_runtime.h>
#include <hip/hip_bf16.h>
#include <cstdint>

typedef __attribute__((ext_vector_type(8))) short bf16x8;   // 8 bf16 (4 VGPRs)
typedef __attribute__((ext_vector_type(4))) short bf16x4;   // 4 bf16 (8 B)
typedef __attribute__((ext_vector_type(4))) float f32x4;    // MFMA C/D

#define BN_EPS 1e-5f

// ---------------------------------------------------------------------------
// sat plane (512 threads): exclusive SAT [129][132] per (b,c) plane.
// Cols 129..131 of every row are ZEROED (eload reads a float2 at x=128).
// ---------------------------------------------------------------------------
__device__ __forceinline__ void sat_plane(const float* __restrict__ xp,
                                          float* __restrict__ Sg, int t)
{
  __shared__ float tile[16384];
  __shared__ float csA[512];
  __shared__ float csB[512];

  for (int i4 = t; i4 < 4096; i4 += 512) {
    int r = i4 >> 5;
    int g = i4 & 31;
    float4 v = *(const float4*)(xp + (size_t)r * 128 + g * 4);
    *(float4*)(tile + r * 128 + ((g ^ (r & 31)) << 2)) = v;
  }
  __syncthreads();

  int r = t & 127, ch = t >> 7;
  {
    float carry = 0.f;
#pragma unroll
    for (int g8 = 0; g8 < 8; ++g8) {
      int g = ch * 8 + g8;
      float* p = tile + r * 128 + ((g ^ (r & 31)) << 2);
      float4 v = *(float4*)p;
      float s0 = carry + v.x, s1 = s0 + v.y, s2 = s1 + v.z, s3 = s2 + v.w;
      float4 o; o.x = s0; o.y = s1; o.z = s2; o.w = s3;
      *(float4*)p = o;
      carry = s3;
    }
    csA[r * 4 + ch] = carry;
  }
  __syncthreads();
  if (ch > 0) {
    float offs = csA[r * 4 + 0];
    if (ch > 1) offs += csA[r * 4 + 1];
    if (ch > 2) offs += csA[r * 4 + 2];
#pragma unroll
    for (int g8 = 0; g8 < 8; ++g8) {
      int g = ch * 8 + g8;
      float* p = tile + r * 128 + ((g ^ (r & 31)) << 2);
      float4 v = *(float4*)p;
      v.x += offs; v.y += offs; v.z += offs; v.w += offs;
      *(float4*)p = v;
    }
  }
  __syncthreads();

  int xcol = t & 127, rc = t >> 7;
  int gc = xcol >> 2, wc = xcol & 3;
  float regs[32];
  {
    float run = 0.f;
#pragma unroll
    for (int r8 = 0; r8 < 32; ++r8) {
      int rr = rc * 32 + r8;
      run += tile[rr * 128 + ((gc ^ (rr & 31)) << 2) + wc];
      regs[r8] = run;
    }
    csB[xcol * 4 + rc] = run;
  }
  if (t < 132) Sg[t] = 0.f;                 // row 0, cols 0..131
  if (t < 128) Sg[(t + 1) * 132] = 0.f;     // col 0
  if (t < 128) {                            // pad cols 129..131, rows 1..128
    float* rp = Sg + (size_t)(t + 1) * 132;
    rp[129] = 0.f; rp[130] = 0.f; rp[131] = 0.f;
  }
  __syncthreads();

  float offs = 0.f;
  if (rc > 0) offs += csB[xcol * 4 + 0];
  if (rc > 1) offs += csB[xcol * 4 + 1];
  if (rc > 2) offs += csB[xcol * 4 + 2];
#pragma unroll
  for (int r8 = 0; r8 < 32; ++r8) {
    int rr = rc * 32 + r8;
    Sg[(rr + 1) * 132 + xcol + 1] = regs[r8] + offs;
  }
}

// ---------------------------------------------------------------------------
// prepsat: blocks [0,512) prep1 (V,b1e); [512,608) prep2 (W2e,b2e);
//          [608,608+nplanes) sat planes.
// ---------------------------------------------------------------------------
__global__ __launch_bounds__(512) void prepsat_kernel(
    const float* __restrict__ W1, const float* __restrict__ cb1,
    const float* __restrict__ g1, const float* __restrict__ be1,
    const float* __restrict__ mu1, const float* __restrict__ va1,
    const float* __restrict__ W2, const float* __restrict__ cb2,
    const float* __restrict__ g2, const float* __restrict__ be2,
    const float* __restrict__ mu2, const float* __restrict__ va2,
    const float* __restrict__ x,
    __hip_bfloat16* __restrict__ V, float* __restrict__ b1e,
    __hip_bfloat16* __restrict__ W2e, float* __restrict__ b2e,
    float* __restrict__ SAT, int nplanes)
{
  int blk = blockIdx.x;
  int t = threadIdx.x;
  if (blk < 512) {
    __shared__ float red[8];
    int o = blk;
    const float* wrow = W1 + (size_t)o * 1248;
    float acc = 0.f;
    for (int i = t; i < 1248; i += 512) {
      float s = g1[i] * rsqrtf(va1[i] + BN_EPS);
      float w = wrow[i];
      acc += w * (be1[i] - mu1[i] * s);
      float g = w * s;
      float gn = 0.f;
      if (i < 1152) {
        float sn = g1[i + 96] * rsqrtf(va1[i + 96] + BN_EPS);
        gn = wrow[i + 96] * sn;
      }
      V[(size_t)o * 1248 + i] = __float2bfloat16(g - gn);
    }
    for (int d = 32; d > 0; d >>= 1) acc += __shfl_down(acc, d);
    int lane = t & 63, wvv = t >> 6;
    if (lane == 0) red[wvv] = acc;
    __syncthreads();
    if (t == 0) {
      float s = cb1[o];
#pragma unroll
      for (int i = 0; i < 8; ++i) s += red[i];
      b1e[o] = s;
    }
  } else if (blk < 608) {
    __shared__ float red2[8];
    int o = blk - 512;
    const float* wrow = W2 + (size_t)o * 512;
    float acc = 0.f;
    {
      int j = t;
      float s = g2[j] * rsqrtf(va2[j] + BN_EPS);
      float wv = wrow[j];
      acc = wv * (be2[j] - mu2[j] * s);
      W2e[(size_t)o * 512 + j] = __float2bfloat16(wv * s);
    }
    for (int d = 32; d > 0; d >>= 1) acc += __shfl_down(acc, d);
    int lane = t & 63, wvv = t >> 6;
    if (lane == 0) red2[wvv] = acc;
    __syncthreads();
    if (t == 0) {
      float s = cb2[o];
#pragma unroll
      for (int i = 0; i < 8; ++i) s += red2[i];
      b2e[o] = s;
    }
  } else {
    int plane = blk - 608;
    if (plane < nplanes)
      sat_plane(x + (size_t)plane * 16384, SAT + (size_t)plane * 17028, t);
  }
}

__global__ __launch_bounds__(512) void satonly_kernel(
    const float* __restrict__ x, float* __restrict__ SAT)
{
  sat_plane(x + (size_t)blockIdx.x * 16384,
            SAT + (size_t)blockIdx.x * 17028, threadIdx.x);
}

// ---------------------------------------------------------------------------
// fused v8: wave specialization with PLAIN BARRIER handoff (no flag protocol).
// Block = (img, y, px-half): 64 out px, 1024 thr = 16 waves.
// Waves {0-3,8-11} producers (P), {4-7,12-15} consumers (C): each SIMD hosts
// 2P + 2C. P-wave p owns channels 12p..12p+11 (ET columns AND As columns are
// channel-private to a producer; ET single-buffered, As double-buffered).
// Phase j (one __syncthreads each): P builds As[(j+1)&1] <- ring j+1 while
// C runs MFMA(ring j) from As[j&1]. acc[4][4] = 64 AGPR -> 128 regs/wave,
// 4 waves/SIMD. In-wave ewrite->build LDS RAW fenced with explicit
// s_waitcnt lgkmcnt(0) + sched_barrier (rule-18 class hazard).
// LDS: ET 36800 + As0/As1 13312*2 = 63424; epilogue Yst[64][520] = 66560
// aliases (dynamic size 66560).
// ---------------------------------------------------------------------------
__global__ __launch_bounds__(1024) void fused3_kernel(
    const float* __restrict__ SAT, const __hip_bfloat16* __restrict__ V,
    const float* __restrict__ b1e, const __hip_bfloat16* __restrict__ W2e,
    const float* __restrict__ b2e, float* __restrict__ out, int nb, int b0)
{
  extern __shared__ __align__(16) char smem[];
  float* ET = (float*)smem;                                  // 92*100*4 = 36800
  __hip_bfloat16* As0 = (__hip_bfloat16*)(smem + 36800);     // 64*104*2 = 13312
  __hip_bfloat16* As1 = (__hip_bfloat16*)(smem + 50112);

  int blk = blockIdx.x;
  int per_xcd = (nb * 256) >> 3;
  int r = (blk & 7) * per_xcd + (blk >> 3);
  int bL = r >> 8;
  int rem = r & 255;
  int y = rem >> 1, h = rem & 1;
  int x0 = h * 64 - 12;                       // ET local row xl <-> global x0+xl
  const float* Sb = SAT + (size_t)bL * 96 * 17028;

  int t = threadIdx.x;
  int lane = t & 63, wv = t >> 6;
  int lr = lane & 15, quad = lane >> 4;
  bool isC = (wv & 4) != 0;                   // SIMD wv&3 hosts 2P + 2C
  int role = (wv & 3) | (((wv >> 3) & 1) << 2);   // 0..7 within role

  f32x4 acc[4][4];
#pragma unroll
  for (int io = 0; io < 4; ++io)
#pragma unroll
    for (int ip = 0; ip < 4; ++ip) acc[io][ip] = (f32x4){0.f, 0.f, 0.f, 0.f};

  int cb = role * 12;                         // producer: private channels
  int pxl = lane;                             // producer: own pixel
  int pxg = h * 64 + pxl;

  // produce ring jr: fill ET (own channels, all 92 rows) then build As rows.
  auto produce = [&](__hip_bfloat16* As, int jr) {
    int y1 = (y - jr < 0 ? 0 : y - jr) * 132;
    int y2 = ((y + jr > 127 ? 127 : y + jr) + 1) * 132;
#pragma unroll
    for (int it = 0; it < 5; ++it) {
      int idx = lane + (it << 6);
      if (idx < 276) {                        // 6 ch-pairs x 46 x-quads
        int clp = idx / 46;
        int xq = idx - clp * 46;
        int cl = cb + clp * 2;
        int xg = x0 + (xq << 1);
        xg = xg < 0 ? 0 : (xg > 128 ? 128 : xg);   // clamped rows never read
        const float* p0 = Sb + (size_t)cl * 17028 + xg;
        float2 a2 = *(const float2*)(p0 + y2);
        float2 a1 = *(const float2*)(p0 + y1);
        float2 c2 = *(const float2*)(p0 + 17028 + y2);
        float2 c1 = *(const float2*)(p0 + 17028 + y1);
        int xl = xq << 1;
        int sw = ((xl >> 3) & 7) << 2;             // XOR-swizzle col bits 2..4
        int cw = cl ^ sw;
        *(float2*)(ET + xl * 100 + cw) = make_float2(a2.x - a1.x, c2.x - c1.x);
        *(float2*)(ET + xl * 100 + 100 + cw) = make_float2(a2.y - a1.y, c2.y - c1.y);
      }
    }
    // in-wave LDS RAW fence: build reads rows written by sibling lanes above
    asm volatile("s_waitcnt lgkmcnt(0)" ::: "memory");
    __builtin_amdgcn_sched_barrier(0);
    int x2l = ((pxg + jr > 127 ? 127 : pxg + jr) + 1) - x0;
    int x1l = ((pxg - jr < 0 ? 0 : pxg - jr)) - x0;
    int s2 = ((x2l >> 3) & 7) << 2;
    int s1 = ((x1l >> 3) & 7) << 2;
    const float* r2 = ET + x2l * 100;
    const float* r1 = ET + x1l * 100;
#pragma unroll
    for (int k = 0; k < 3; ++k) {
      int c = cb + (k << 2);
      float4 e2 = *(const float4*)(r2 + (c ^ s2));
      float4 e1 = *(const float4*)(r1 + (c ^ s1));
      union { bf16x4 v; __hip_bfloat16 hh[4]; } pk;
      pk.hh[0] = __float2bfloat16(e2.x - e1.x);
      pk.hh[1] = __float2bfloat16(e2.y - e1.y);
      pk.hh[2] = __float2bfloat16(e2.z - e1.z);
      pk.hh[3] = __float2bfloat16(e2.w - e1.w);
      *(bf16x4*)(As + pxl * 104 + c) = pk.v;
    }
  };

  // consumer: 48 MFMA for ring j (o1-slab role*64, px 0..63)
  const __hip_bfloat16* Vb = V + (size_t)(role * 64) * 1248;
  auto mfma_ring = [&](int j, const __hip_bfloat16* As) {
#pragma unroll
    for (int sub = 0; sub < 3; ++sub) {
      bf16x8 av[4], bs[4];
#pragma unroll
      for (int io = 0; io < 4; ++io)
        av[io] = *(const bf16x8*)(Vb + (size_t)(io * 16 + lr) * 1248
                                  + j * 96 + sub * 32 + quad * 8);
#pragma unroll
      for (int ip = 0; ip < 4; ++ip)
        bs[ip] = *(const bf16x8*)(As + (ip * 16 + lr) * 104 + sub * 32 + quad * 8);
      __builtin_amdgcn_s_setprio(1);
#pragma unroll
      for (int io = 0; io < 4; ++io)
#pragma unroll
        for (int ip = 0; ip < 4; ++ip)
          acc[io][ip] = __builtin_amdgcn_mfma_f32_16x16x32_bf16(
              av[io], bs[ip], acc[io][ip], 0, 0, 0);
      __builtin_amdgcn_s_setprio(0);
    }
  };

  // prologue: producers build ring 0 into As0
  if (!isC) produce(As0, 0);
  __syncthreads();

  // main loop: one barrier per ring; P one ring ahead of C
  for (int j = 0; j < 13; ++j) {
    if (!isC) {
      if (j < 12) produce((j & 1) ? As0 : As1, j + 1);   // target parity (j+1)&1
    } else {
      mfma_ring(j, (j & 1) ? As1 : As0);
    }
    __syncthreads();
  }

  // ---- epilogue A: bias+relu -> Yst[64 px][520 o1] bf16 (C-waves) ----
  __hip_bfloat16* Yst = (__hip_bfloat16*)smem;   // 64*520*2 = 66560 B
  if (isC) {
#pragma unroll
    for (int io = 0; io < 4; ++io) {
      int o1b = role * 64 + io * 16 + quad * 4;
      float4 bias = *(const float4*)(b1e + o1b);
#pragma unroll
      for (int ip = 0; ip < 4; ++ip) {
        int pxx = ip * 16 + lr;
        f32x4 a = acc[io][ip];
        float z0 = a[0] + bias.x; z0 = z0 > 0.f ? z0 : 0.f;
        float z1 = a[1] + bias.y; z1 = z1 > 0.f ? z1 : 0.f;
        float z2 = a[2] + bias.z; z2 = z2 > 0.f ? z2 : 0.f;
        float z3 = a[3] + bias.w; z3 = z3 > 0.f ? z3 : 0.f;
        union { bf16x4 v; __hip_bfloat16 hh[4]; } pk;
        pk.hh[0] = __float2bfloat16(z0); pk.hh[1] = __float2bfloat16(z1);
        pk.hh[2] = __float2bfloat16(z2); pk.hh[3] = __float2bfloat16(z3);
        *(bf16x4*)(Yst + pxx * 520 + o1b) = pk.v;
      }
    }
  }
  __syncthreads();

  // ---- epilogue B: out[96 o2][64 px] = W2e[96][512] x Yst^T (C-waves) ----
  if (isC) {
    int mh = role >> 2;        // 0: o2 0..47, 1: 48..95
    int pq = role & 3;         // px quarter
    f32x4 acc2[3];
#pragma unroll
    for (int im = 0; im < 3; ++im) acc2[im] = (f32x4){0.f, 0.f, 0.f, 0.f};
    for (int k2 = 0; k2 < 512; k2 += 32) {
      bf16x8 b2f = *(const bf16x8*)(Yst + (pq * 16 + lr) * 520 + k2 + quad * 8);
#pragma unroll
      for (int im = 0; im < 3; ++im) {
        bf16x8 a2f = *(const bf16x8*)(W2e + (size_t)(mh * 48 + im * 16 + lr) * 512
                                      + k2 + quad * 8);
        acc2[im] = __builtin_amdgcn_mfma_f32_16x16x32_bf16(a2f, b2f, acc2[im], 0, 0, 0);
      }
    }
    size_t obase = ((size_t)(b0 + bL) * 96) * 16384 + (size_t)y * 128
                   + h * 64 + pq * 16 + lr;
#pragma unroll
    for (int im = 0; im < 3; ++im) {
#pragma unroll
      for (int rr = 0; rr < 4; ++rr) {
        int o2 = mh * 48 + im * 16 + quad * 4 + rr;
        out[obase + (size_t)o2 * 16384] = acc2[im][rr] + b2e[o2];
      }
    }
  }
}

// ---------------------------------------------------------------------------
extern "C" void kernel_launch(void* const* d_in, const int* in_sizes, int n_in,
                              void* d_out, int out_size, void* d_ws, size_t ws_size,
                              hipStream_t stream)
{
  const float* x   = (const float*)d_in[0];
  const float* g1  = (const float*)d_in[1];
  const float* be1 = (const float*)d_in[2];
  const float* mu1 = (const float*)d_in[3];
  const float* va1 = (const float*)d_in[4];
  const float* W1  = (const float*)d_in[5];
  const float* cb1 = (const float*)d_in[6];
  const float* g2  = (const float*)d_in[7];
  const float* be2 = (const float*)d_in[8];
  const float* mu2 = (const float*)d_in[9];
  const float* va2 = (const float*)d_in[10];
  const float* W2  = (const float*)d_in[11];
  const float* cb2 = (const float*)d_in[12];
  float* out = (float*)d_out;

  hipFuncSetAttribute((const void*)fused3_kernel,
                      hipFuncAttributeMaxDynamicSharedMemorySize, 66560);

  char* w = (char*)d_ws;
  __hip_bfloat16* V   = (__hip_bfloat16*)w; w += (size_t)512 * 1248 * 2;
  __hip_bfloat16* W2e = (__hip_bfloat16*)w; w += (size_t)96 * 512 * 2;
  float* b1e = (float*)w; w += 2048;
  float* b2e = (float*)w; w += 512;
  size_t fixed = (size_t)(w - (char*)d_ws);

  const size_t satB = (size_t)96 * 17028 * 4;     // per-batch SAT bytes
  int nb = (ws_size >= fixed + 4 * satB + 4096) ? 4 : 1;

  float* SAT = (float*)w;

  if (nb == 4) {
    prepsat_kernel<<<992, 512, 0, stream>>>(W1, cb1, g1, be1, mu1, va1,
                                            W2, cb2, g2, be2, mu2, va2,
                                            x, V, b1e, W2e, b2e, SAT, 384);
    fused3_kernel<<<1024, 1024, 66560, stream>>>(SAT, V, b1e, W2e, b2e, out, 4, 0);
  } else {
    prepsat_kernel<<<608, 512, 0, stream>>>(W1, cb1, g1, be1, mu1, va1,
                                            W2, cb2, g2, be2, mu2, va2,
                                            x, V, b1e, W2e, b2e, SAT, 0);
    for (int b0 = 0; b0 < 4; ++b0) {
      satonly_kernel<<<96, 512, 0, stream>>>(x + (size_t)b0 * 96 * 16384, SAT);
      fused3_kernel<<<256, 1024, 66560, stream>>>(SAT, V, b1e, W2e, b2e, out, 1, b0);
    }
  }
}

// Round 5
// 347.699 us; speedup vs baseline: 1.1467x; 1.1467x over previous
//
#include <hip/hip_runtime.h>
#include <hip/hip_bf16.h>
#include <cstdint>

typedef __attribute__((ext_vector_type(8))) short bf16x8;   // 8 bf16 (4 VGPRs)
typedef __attribute__((ext_vector_type(4))) short bf16x4;   // 4 bf16 (8 B)
typedef __attribute__((ext_vector_type(4))) float f32x4;    // MFMA C/D

#define BN_EPS 1e-5f

// ---------------------------------------------------------------------------
// sat plane (512 threads): exclusive SAT [129][132] per (b,c) plane.
// Cols 129..131 of every row zeroed (eload reads float2 at x=128).
// ---------------------------------------------------------------------------
__device__ __forceinline__ void sat_plane(const float* __restrict__ xp,
                                          float* __restrict__ Sg, int t)
{
  __shared__ float tile[16384];
  __shared__ float csA[512];
  __shared__ float csB[512];

  for (int i4 = t; i4 < 4096; i4 += 512) {
    int r = i4 >> 5;
    int g = i4 & 31;
    float4 v = *(const float4*)(xp + (size_t)r * 128 + g * 4);
    *(float4*)(tile + r * 128 + ((g ^ (r & 31)) << 2)) = v;
  }
  __syncthreads();

  int r = t & 127, ch = t >> 7;
  {
    float carry = 0.f;
#pragma unroll
    for (int g8 = 0; g8 < 8; ++g8) {
      int g = ch * 8 + g8;
      float* p = tile + r * 128 + ((g ^ (r & 31)) << 2);
      float4 v = *(float4*)p;
      float s0 = carry + v.x, s1 = s0 + v.y, s2 = s1 + v.z, s3 = s2 + v.w;
      float4 o; o.x = s0; o.y = s1; o.z = s2; o.w = s3;
      *(float4*)p = o;
      carry = s3;
    }
    csA[r * 4 + ch] = carry;
  }
  __syncthreads();
  if (ch > 0) {
    float offs = csA[r * 4 + 0];
    if (ch > 1) offs += csA[r * 4 + 1];
    if (ch > 2) offs += csA[r * 4 + 2];
#pragma unroll
    for (int g8 = 0; g8 < 8; ++g8) {
      int g = ch * 8 + g8;
      float* p = tile + r * 128 + ((g ^ (r & 31)) << 2);
      float4 v = *(float4*)p;
      v.x += offs; v.y += offs; v.z += offs; v.w += offs;
      *(float4*)p = v;
    }
  }
  __syncthreads();

  int xcol = t & 127, rc = t >> 7;
  int gc = xcol >> 2, wc = xcol & 3;
  float regs[32];
  {
    float run = 0.f;
#pragma unroll
    for (int r8 = 0; r8 < 32; ++r8) {
      int rr = rc * 32 + r8;
      run += tile[rr * 128 + ((gc ^ (rr & 31)) << 2) + wc];
      regs[r8] = run;
    }
    csB[xcol * 4 + rc] = run;
  }
  if (t < 132) Sg[t] = 0.f;                 // row 0, cols 0..131
  if (t < 128) Sg[(t + 1) * 132] = 0.f;     // col 0
  if (t < 128) {                            // pad cols 129..131
    float* rp = Sg + (size_t)(t + 1) * 132;
    rp[129] = 0.f; rp[130] = 0.f; rp[131] = 0.f;
  }
  __syncthreads();

  float offs = 0.f;
  if (rc > 0) offs += csB[xcol * 4 + 0];
  if (rc > 1) offs += csB[xcol * 4 + 1];
  if (rc > 2) offs += csB[xcol * 4 + 2];
#pragma unroll
  for (int r8 = 0; r8 < 32; ++r8) {
    int rr = rc * 32 + r8;
    Sg[(rr + 1) * 132 + xcol + 1] = regs[r8] + offs;
  }
}

// ---------------------------------------------------------------------------
// prepsat: blocks [0,512) prep1; [512,608) prep2; [608,608+nplanes) sat.
// ---------------------------------------------------------------------------
__global__ __launch_bounds__(512) void prepsat_kernel(
    const float* __restrict__ W1, const float* __restrict__ cb1,
    const float* __restrict__ g1, const float* __restrict__ be1,
    const float* __restrict__ mu1, const float* __restrict__ va1,
    const float* __restrict__ W2, const float* __restrict__ cb2,
    const float* __restrict__ g2, const float* __restrict__ be2,
    const float* __restrict__ mu2, const float* __restrict__ va2,
    const float* __restrict__ x,
    __hip_bfloat16* __restrict__ V, float* __restrict__ b1e,
    __hip_bfloat16* __restrict__ W2e, float* __restrict__ b2e,
    float* __restrict__ SAT, int nplanes)
{
  int blk = blockIdx.x;
  int t = threadIdx.x;
  if (blk < 512) {
    __shared__ float red[8];
    int o = blk;
    const float* wrow = W1 + (size_t)o * 1248;
    float acc = 0.f;
    for (int i = t; i < 1248; i += 512) {
      float s = g1[i] * rsqrtf(va1[i] + BN_EPS);
      float w = wrow[i];
      acc += w * (be1[i] - mu1[i] * s);
      float g = w * s;
      float gn = 0.f;
      if (i < 1152) {
        float sn = g1[i + 96] * rsqrtf(va1[i + 96] + BN_EPS);
        gn = wrow[i + 96] * sn;
      }
      V[(size_t)o * 1248 + i] = __float2bfloat16(g - gn);
    }
    for (int d = 32; d > 0; d >>= 1) acc += __shfl_down(acc, d);
    int lane = t & 63, wvv = t >> 6;
    if (lane == 0) red[wvv] = acc;
    __syncthreads();
    if (t == 0) {
      float s = cb1[o];
#pragma unroll
      for (int i = 0; i < 8; ++i) s += red[i];
      b1e[o] = s;
    }
  } else if (blk < 608) {
    __shared__ float red2[8];
    int o = blk - 512;
    const float* wrow = W2 + (size_t)o * 512;
    float acc;
    {
      int j = t;
      float s = g2[j] * rsqrtf(va2[j] + BN_EPS);
      float wv = wrow[j];
      acc = wv * (be2[j] - mu2[j] * s);
      W2e[(size_t)o * 512 + j] = __float2bfloat16(wv * s);
    }
    for (int d = 32; d > 0; d >>= 1) acc += __shfl_down(acc, d);
    int lane = t & 63, wvv = t >> 6;
    if (lane == 0) red2[wvv] = acc;
    __syncthreads();
    if (t == 0) {
      float s = cb2[o];
#pragma unroll
      for (int i = 0; i < 8; ++i) s += red2[i];
      b2e[o] = s;
    }
  } else {
    int plane = blk - 608;
    if (plane < nplanes)
      sat_plane(x + (size_t)plane * 16384, SAT + (size_t)plane * 17028, t);
  }
}

__global__ __launch_bounds__(512) void satonly_kernel(
    const float* __restrict__ x, float* __restrict__ SAT)
{
  sat_plane(x + (size_t)blockIdx.x * 16384,
            SAT + (size_t)blockIdx.x * 17028, threadIdx.x);
}

// ---------------------------------------------------------------------------
// fused v9: R2's verified monolithic T14 schedule + transposed-swizzled ET.
// 512 thr / 8 waves / 256 regs (launch_bounds(512,2)); wave tile M128xN64,
// acc[8][4]. ET[x:130][c stride 100w] f32, XOR-swizzle cw = c ^ ((x>>3&7)<<2):
// build(ring) = 12 ds_read_b128 + 24 cvt + 6 b64 As-writes per thread
// (was 48 scalar b32 reads in R2 -> LDS pipe was the measured wall).
// As double-buffered -> ONE barrier per ring; eload/ewrite (T14 split) and
// build interleaved between the 3 MFMA sub-phases so each wave's own MFMA
// hides its loads, and waves slide freely within the phase.
// LDS: ET0/ET1 52000 ea + As0/As1 26624 ea = 157248; Yst[128][520]=133120
// aliases for the epilogues. 1 block/CU.
// ---------------------------------------------------------------------------
__global__ __launch_bounds__(512, 2) void fused4_kernel(
    const float* __restrict__ SAT, const __hip_bfloat16* __restrict__ V,
    const float* __restrict__ b1e, const __hip_bfloat16* __restrict__ W2e,
    const float* __restrict__ b2e, float* __restrict__ out, int nb, int b0)
{
  extern __shared__ __align__(16) char smem[];
  float* ET0 = (float*)smem;                                  // 130*100*4 = 52000
  float* ET1 = (float*)(smem + 52000);
  __hip_bfloat16* As0 = (__hip_bfloat16*)(smem + 104000);     // 128*104*2 = 26624
  __hip_bfloat16* As1 = (__hip_bfloat16*)(smem + 130624);

  int blk = blockIdx.x;
  int per_xcd = (nb * 128) >> 3;
  int r = (blk & 7) * per_xcd + (blk >> 3);
  int bL = r >> 7, y = r & 127;

  int t = threadIdx.x;
  int lane = t & 63, wv = t >> 6;              // 8 waves
  int wo = wv >> 1, wp = wv & 1;               // o1-slab (128), px-half (64)
  int lr = lane & 15, quad = lane >> 4;
  int bpx = t & 127;                           // build pixel
  int bg24 = t >> 7;                           // build channel-group (24 ch)

  const float* Sb = SAT + (size_t)bL * 96 * 17028;

  f32x4 acc[8][4];
#pragma unroll
  for (int io = 0; io < 8; ++io)
#pragma unroll
    for (int ip = 0; ip < 4; ++ip) acc[io][ip] = (f32x4){0.f, 0.f, 0.f, 0.f};

  // ---- eload/ewrite: 48 ch-pairs x 65 x-float2 = 3120 tasks, T14 split.
  //      h0 = tasks [0,1536) (3 slots, no bounds check); h1 = [1536,3120).
  float2 a2[4], a1[4], c2[4], c1[4];

  auto eload = [&](int jr, int h) {
    int y1 = ((y - jr < 0) ? 0 : (y - jr)) * 132;
    int y2 = (((y + jr > 127) ? 127 : (y + jr)) + 1) * 132;
    int n = h ? 4 : 3, base = h ? 1536 : 0;
#pragma unroll
    for (int k = 0; k < 4; ++k) {
      if (k >= n) break;
      int idx = base + t + 512 * k;
      if (idx < 3120) {
        int clp = idx / 65;
        int xq = idx - clp * 65;
        const float* p0 = Sb + (size_t)(2 * clp) * 17028 + 2 * xq;
        a2[k] = *(const float2*)(p0 + y2);
        a1[k] = *(const float2*)(p0 + y1);
        c2[k] = *(const float2*)(p0 + 17028 + y2);
        c1[k] = *(const float2*)(p0 + 17028 + y1);
      }
    }
  };

  auto ewrite = [&](float* ET, int h) {
    int n = h ? 4 : 3, base = h ? 1536 : 0;
#pragma unroll
    for (int k = 0; k < 4; ++k) {
      if (k >= n) break;
      int idx = base + t + 512 * k;
      if (idx < 3120) {
        int clp = idx / 65;
        int xq = idx - clp * 65;
        int xl = xq * 2, cl = clp * 2;
        int cw = cl ^ (((xl >> 3) & 7) << 2);
        float2 d0, d1;
        d0.x = a2[k].x - a1[k].x; d0.y = c2[k].x - c1[k].x;
        d1.x = a2[k].y - a1[k].y; d1.y = c2[k].y - c1[k].y;
        *(float2*)(ET + xl * 100 + cw) = d0;          // row xl:   ch cl, cl+1
        *(float2*)(ET + (xl + 1) * 100 + cw) = d1;    // row xl+1: ch cl, cl+1
      }
    }
  };

  // build half: 12 channels (3 float4-pairs) for pixel bpx of ring jr
  auto build_h = [&](const float* ET, __hip_bfloat16* As, int jr, int half) {
    int x2 = ((bpx + jr > 127) ? 127 : (bpx + jr)) + 1;
    int x1 = (bpx - jr < 0) ? 0 : (bpx - jr);
    int s2 = ((x2 >> 3) & 7) << 2;
    int s1 = ((x1 >> 3) & 7) << 2;
    const float* r2 = ET + x2 * 100;
    const float* r1 = ET + x1 * 100;
#pragma unroll
    for (int k = 0; k < 3; ++k) {
      int c = bg24 * 24 + half * 12 + 4 * k;
      float4 e2 = *(const float4*)(r2 + (c ^ s2));
      float4 e1 = *(const float4*)(r1 + (c ^ s1));
      union { bf16x4 v; __hip_bfloat16 hh[4]; } pk;
      pk.hh[0] = __float2bfloat16(e2.x - e1.x);
      pk.hh[1] = __float2bfloat16(e2.y - e1.y);
      pk.hh[2] = __float2bfloat16(e2.z - e1.z);
      pk.hh[3] = __float2bfloat16(e2.w - e1.w);
      *(bf16x4*)(As + bpx * 104 + c) = pk.v;
    }
  };

  // one K-sub-phase: 8 V-frags (global) x 4 As-frags (LDS) -> 32 MFMA
  auto mfma_sub = [&](int j, int sub, const __hip_bfloat16* As) {
    bf16x8 av[8], bs[4];
#pragma unroll
    for (int io = 0; io < 8; ++io)
      av[io] = *(const bf16x8*)(V + (size_t)(wo * 128 + io * 16 + lr) * 1248
                                + j * 96 + sub * 32 + quad * 8);
#pragma unroll
    for (int ip = 0; ip < 4; ++ip)
      bs[ip] = *(const bf16x8*)(As + (wp * 64 + ip * 16 + lr) * 104 + sub * 32 + quad * 8);
    __builtin_amdgcn_s_setprio(1);
#pragma unroll
    for (int io = 0; io < 8; ++io)
#pragma unroll
      for (int ip = 0; ip < 4; ++ip)
        acc[io][ip] = __builtin_amdgcn_mfma_f32_16x16x32_bf16(av[io], bs[ip], acc[io][ip], 0, 0, 0);
    __builtin_amdgcn_s_setprio(0);
  };

  // ---- prologue: ET0 <- ring0; As0 <- ring0 and ET1 <- ring1 ----
  eload(0, 0); ewrite(ET0, 0); eload(0, 1); ewrite(ET0, 1);
  __syncthreads();
  eload(1, 0); ewrite(ET1, 0);
  build_h(ET0, As0, 0, 0);
  eload(1, 1); ewrite(ET1, 1);
  build_h(ET0, As0, 0, 1);
  __syncthreads();

  // ---- main loop: ONE barrier per ring ----
  for (int j = 0; j < 13; ++j) {
    float* ETw = (j & 1) ? ET1 : ET0;            // ring j+2 target
    const float* ETr = (j & 1) ? ET0 : ET1;      // ring j+1 source
    const __hip_bfloat16* Asr = (j & 1) ? As1 : As0;   // ring j
    __hip_bfloat16* Asw = (j & 1) ? As0 : As1;         // ring j+1
    bool pf = (j < 11), bd = (j < 12);
    if (pf) eload(j + 2, 0);
    mfma_sub(j, 0, Asr);
    if (pf) { ewrite(ETw, 0); eload(j + 2, 1); }
    if (bd) build_h(ETr, Asw, j + 1, 0);
    mfma_sub(j, 1, Asr);
    if (pf) ewrite(ETw, 1);
    if (bd) build_h(ETr, Asw, j + 1, 1);
    mfma_sub(j, 2, Asr);
    __syncthreads();
  }

  // ---- epilogue A: bias+relu -> Yst[128 px][520 o1] bf16, b64 writes ----
  __hip_bfloat16* Yst = (__hip_bfloat16*)smem;   // 128*520*2 = 133120 B
#pragma unroll
  for (int io = 0; io < 8; ++io) {
    int o1b = wo * 128 + io * 16 + quad * 4;
    float4 bias = *(const float4*)(b1e + o1b);
#pragma unroll
    for (int ip = 0; ip < 4; ++ip) {
      int pxx = wp * 64 + ip * 16 + lr;
      f32x4 a = acc[io][ip];
      float z0 = a[0] + bias.x; z0 = z0 > 0.f ? z0 : 0.f;
      float z1 = a[1] + bias.y; z1 = z1 > 0.f ? z1 : 0.f;
      float z2 = a[2] + bias.z; z2 = z2 > 0.f ? z2 : 0.f;
      float z3 = a[3] + bias.w; z3 = z3 > 0.f ? z3 : 0.f;
      union { bf16x4 v; __hip_bfloat16 hh[4]; } pk;
      pk.hh[0] = __float2bfloat16(z0); pk.hh[1] = __float2bfloat16(z1);
      pk.hh[2] = __float2bfloat16(z2); pk.hh[3] = __float2bfloat16(z3);
      *(bf16x4*)(Yst + pxx * 520 + o1b) = pk.v;
    }
  }
  __syncthreads();

  // ---- epilogue B: out[96 o2][128 px] = W2e[96][512] x Yst^T ----
  int og = wv >> 2;          // 0,1
  int pg = wv & 3;           // 0..3
  f32x4 acc2[3][2];
#pragma unroll
  for (int im = 0; im < 3; ++im)
#pragma unroll
    for (int tl = 0; tl < 2; ++tl) acc2[im][tl] = (f32x4){0.f, 0.f, 0.f, 0.f};

  for (int k2 = 0; k2 < 512; k2 += 32) {
    bf16x8 bfr2[2];
#pragma unroll
    for (int tl = 0; tl < 2; ++tl)
      bfr2[tl] = *(const bf16x8*)(Yst + (pg * 32 + tl * 16 + lr) * 520 + k2 + quad * 8);
#pragma unroll
    for (int im = 0; im < 3; ++im) {
      bf16x8 afr2 = *(const bf16x8*)(W2e + (size_t)(og * 48 + im * 16 + lr) * 512
                                     + k2 + quad * 8);
#pragma unroll
      for (int tl = 0; tl < 2; ++tl)
        acc2[im][tl] = __builtin_amdgcn_mfma_f32_16x16x32_bf16(afr2, bfr2[tl], acc2[im][tl], 0, 0, 0);
    }
  }

  size_t obase = ((size_t)(b0 + bL) * 96) * 16384 + (size_t)y * 128;
#pragma unroll
  for (int im = 0; im < 3; ++im) {
#pragma unroll
    for (int tl = 0; tl < 2; ++tl) {
      int pxx = pg * 32 + tl * 16 + lr;
#pragma unroll
      for (int rr = 0; rr < 4; ++rr) {
        int o2 = og * 48 + im * 16 + quad * 4 + rr;
        out[obase + (size_t)o2 * 16384 + pxx] = acc2[im][tl][rr] + b2e[o2];
      }
    }
  }
}

// ---------------------------------------------------------------------------
extern "C" void kernel_launch(void* const* d_in, const int* in_sizes, int n_in,
                              void* d_out, int out_size, void* d_ws, size_t ws_size,
                              hipStream_t stream)
{
  const float* x   = (const float*)d_in[0];
  const float* g1  = (const float*)d_in[1];
  const float* be1 = (const float*)d_in[2];
  const float* mu1 = (const float*)d_in[3];
  const float* va1 = (const float*)d_in[4];
  const float* W1  = (const float*)d_in[5];
  const float* cb1 = (const float*)d_in[6];
  const float* g2  = (const float*)d_in[7];
  const float* be2 = (const float*)d_in[8];
  const float* mu2 = (const float*)d_in[9];
  const float* va2 = (const float*)d_in[10];
  const float* W2  = (const float*)d_in[11];
  const float* cb2 = (const float*)d_in[12];
  float* out = (float*)d_out;

  hipFuncSetAttribute((const void*)fused4_kernel,
                      hipFuncAttributeMaxDynamicSharedMemorySize, 157248);

  char* w = (char*)d_ws;
  __hip_bfloat16* V   = (__hip_bfloat16*)w; w += (size_t)512 * 1248 * 2;
  __hip_bfloat16* W2e = (__hip_bfloat16*)w; w += (size_t)96 * 512 * 2;
  float* b1e = (float*)w; w += 2048;
  float* b2e = (float*)w; w += 512;
  size_t fixed = (size_t)(w - (char*)d_ws);

  const size_t satB = (size_t)96 * 17028 * 4;     // per-batch SAT bytes
  int nb = (ws_size >= fixed + 4 * satB + 4096) ? 4 : 1;

  float* SAT = (float*)w;

  if (nb == 4) {
    prepsat_kernel<<<992, 512, 0, stream>>>(W1, cb1, g1, be1, mu1, va1,
                                            W2, cb2, g2, be2, mu2, va2,
                                            x, V, b1e, W2e, b2e, SAT, 384);
    fused4_kernel<<<512, 512, 157248, stream>>>(SAT, V, b1e, W2e, b2e, out, 4, 0);
  } else {
    prepsat_kernel<<<608, 512, 0, stream>>>(W1, cb1, g1, be1, mu1, va1,
                                            W2, cb2, g2, be2, mu2, va2,
                                            x, V, b1e, W2e, b2e, SAT, 0);
    for (int b0 = 0; b0 < 4; ++b0) {
      satonly_kernel<<<96, 512, 0, stream>>>(x + (size_t)b0 * 96 * 16384, SAT);
      fused4_kernel<<<128, 512, 157248, stream>>>(SAT, V, b1e, W2e, b2e, out, 1, b0);
    }
  }
}

// Round 6
// 336.208 us; speedup vs baseline: 1.1859x; 1.0342x over previous
//
#include <hip/hip_runtime.h>
#include <hip/hip_bf16.h>
#include <cstdint>

typedef __attribute__((ext_vector_type(8))) short bf16x8;   // 8 bf16 (4 VGPRs)
typedef __attribute__((ext_vector_type(4))) short bf16x4;   // 4 bf16 (8 B)
typedef __attribute__((ext_vector_type(4))) float f32x4;    // MFMA C/D

#define BN_EPS 1e-5f

// ---------------------------------------------------------------------------
// sat plane (512 threads): exclusive SAT [129][132] per (b,c) plane.
// Cols 129..131 zeroed (eload granule at x=128 reads them).
// ---------------------------------------------------------------------------
__device__ __forceinline__ void sat_plane(const float* __restrict__ xp,
                                          float* __restrict__ Sg, int t)
{
  __shared__ float tile[16384];
  __shared__ float csA[512];
  __shared__ float csB[512];

  for (int i4 = t; i4 < 4096; i4 += 512) {
    int r = i4 >> 5;
    int g = i4 & 31;
    float4 v = *(const float4*)(xp + (size_t)r * 128 + g * 4);
    *(float4*)(tile + r * 128 + ((g ^ (r & 31)) << 2)) = v;
  }
  __syncthreads();

  int r = t & 127, ch = t >> 7;
  {
    float carry = 0.f;
#pragma unroll
    for (int g8 = 0; g8 < 8; ++g8) {
      int g = ch * 8 + g8;
      float* p = tile + r * 128 + ((g ^ (r & 31)) << 2);
      float4 v = *(float4*)p;
      float s0 = carry + v.x, s1 = s0 + v.y, s2 = s1 + v.z, s3 = s2 + v.w;
      float4 o; o.x = s0; o.y = s1; o.z = s2; o.w = s3;
      *(float4*)p = o;
      carry = s3;
    }
    csA[r * 4 + ch] = carry;
  }
  __syncthreads();
  if (ch > 0) {
    float offs = csA[r * 4 + 0];
    if (ch > 1) offs += csA[r * 4 + 1];
    if (ch > 2) offs += csA[r * 4 + 2];
#pragma unroll
    for (int g8 = 0; g8 < 8; ++g8) {
      int g = ch * 8 + g8;
      float* p = tile + r * 128 + ((g ^ (r & 31)) << 2);
      float4 v = *(float4*)p;
      v.x += offs; v.y += offs; v.z += offs; v.w += offs;
      *(float4*)p = v;
    }
  }
  __syncthreads();

  int xcol = t & 127, rc = t >> 7;
  int gc = xcol >> 2, wc = xcol & 3;
  float regs[32];
  {
    float run = 0.f;
#pragma unroll
    for (int r8 = 0; r8 < 32; ++r8) {
      int rr = rc * 32 + r8;
      run += tile[rr * 128 + ((gc ^ (rr & 31)) << 2) + wc];
      regs[r8] = run;
    }
    csB[xcol * 4 + rc] = run;
  }
  if (t < 132) Sg[t] = 0.f;                 // row 0, cols 0..131
  if (t < 128) Sg[(t + 1) * 132] = 0.f;     // col 0
  if (t < 128) {                            // pad cols 129..131
    float* rp = Sg + (size_t)(t + 1) * 132;
    rp[129] = 0.f; rp[130] = 0.f; rp[131] = 0.f;
  }
  __syncthreads();

  float offs = 0.f;
  if (rc > 0) offs += csB[xcol * 4 + 0];
  if (rc > 1) offs += csB[xcol * 4 + 1];
  if (rc > 2) offs += csB[xcol * 4 + 2];
#pragma unroll
  for (int r8 = 0; r8 < 32; ++r8) {
    int rr = rc * 32 + r8;
    Sg[(rr + 1) * 132 + xcol + 1] = regs[r8] + offs;
  }
}

// ---------------------------------------------------------------------------
// prepsat: blocks [0,512) prep1; [512,608) prep2; [608,608+nplanes) sat.
// ---------------------------------------------------------------------------
__global__ __launch_bounds__(512) void prepsat_kernel(
    const float* __restrict__ W1, const float* __restrict__ cb1,
    const float* __restrict__ g1, const float* __restrict__ be1,
    const float* __restrict__ mu1, const float* __restrict__ va1,
    const float* __restrict__ W2, const float* __restrict__ cb2,
    const float* __restrict__ g2, const float* __restrict__ be2,
    const float* __restrict__ mu2, const float* __restrict__ va2,
    const float* __restrict__ x,
    __hip_bfloat16* __restrict__ V, float* __restrict__ b1e,
    __hip_bfloat16* __restrict__ W2e, float* __restrict__ b2e,
    float* __restrict__ SAT, int nplanes)
{
  int blk = blockIdx.x;
  int t = threadIdx.x;
  if (blk < 512) {
    __shared__ float red[8];
    int o = blk;
    const float* wrow = W1 + (size_t)o * 1248;
    float acc = 0.f;
    for (int i = t; i < 1248; i += 512) {
      float s = g1[i] * rsqrtf(va1[i] + BN_EPS);
      float w = wrow[i];
      acc += w * (be1[i] - mu1[i] * s);
      float g = w * s;
      float gn = 0.f;
      if (i < 1152) {
        float sn = g1[i + 96] * rsqrtf(va1[i + 96] + BN_EPS);
        gn = wrow[i + 96] * sn;
      }
      V[(size_t)o * 1248 + i] = __float2bfloat16(g - gn);
    }
    for (int d = 32; d > 0; d >>= 1) acc += __shfl_down(acc, d);
    int lane = t & 63, wvv = t >> 6;
    if (lane == 0) red[wvv] = acc;
    __syncthreads();
    if (t == 0) {
      float s = cb1[o];
#pragma unroll
      for (int i = 0; i < 8; ++i) s += red[i];
      b1e[o] = s;
    }
  } else if (blk < 608) {
    __shared__ float red2[8];
    int o = blk - 512;
    const float* wrow = W2 + (size_t)o * 512;
    float acc;
    {
      int j = t;
      float s = g2[j] * rsqrtf(va2[j] + BN_EPS);
      float wv = wrow[j];
      acc = wv * (be2[j] - mu2[j] * s);
      W2e[(size_t)o * 512 + j] = __float2bfloat16(wv * s);
    }
    for (int d = 32; d > 0; d >>= 1) acc += __shfl_down(acc, d);
    int lane = t & 63, wvv = t >> 6;
    if (lane == 0) red2[wvv] = acc;
    __syncthreads();
    if (t == 0) {
      float s = cb2[o];
#pragma unroll
      for (int i = 0; i < 8; ++i) s += red2[i];
      b2e[o] = s;
    }
  } else {
    int plane = blk - 608;
    if (plane < nplanes)
      sat_plane(x + (size_t)plane * 16384, SAT + (size_t)plane * 17028, t);
  }
}

__global__ __launch_bounds__(512) void satonly_kernel(
    const float* __restrict__ x, float* __restrict__ SAT)
{
  sat_plane(x + (size_t)blockIdx.x * 16384,
            SAT + (size_t)blockIdx.x * 17028, threadIdx.x);
}

// ---------------------------------------------------------------------------
// fused v10: 64-px blocks, 2 blocks/CU (the occupancy lever).
// 512 thr / 8 waves / __launch_bounds__(512,4) -> 128 regs/wave
// (acc[4][4]=64 AGPR + ~60 VGPR). Wave = o1-slab 64 x all 64 px.
// LDS per block: E[96][92] f32 (35328) + As[64][104] bf16 (13312) = 48640;
// epilogue Yst[64][520] bf16 = 66560 aliases -> dynamic 66560 -> 2 blocks/CU,
// 4 waves/SIMD + cross-block phase stagger (barrier never idles the CU).
// Ring phases: P1 { mfma(j) x3 interleaved with eload/ewrite(E <- ring j+1)
// (R2's verified T14 pattern, E[c][x] layout: coalesced float4 ewrite,
// conflict-free scalar build reads) } bar; P2 { build(As <- E) } bar.
// Data-path math identical to R2/R4 (both harness-verified).
// ---------------------------------------------------------------------------
__global__ __launch_bounds__(512, 4) void fused5_kernel(
    const float* __restrict__ SAT, const __hip_bfloat16* __restrict__ V,
    const float* __restrict__ b1e, const __hip_bfloat16* __restrict__ W2e,
    const float* __restrict__ b2e, float* __restrict__ out, int nb, int b0)
{
  extern __shared__ __align__(16) char smem[];
  float* E = (float*)smem;                                   // [96][92] f32
  __hip_bfloat16* As = (__hip_bfloat16*)(smem + 35328);      // [64][104] bf16

  int blk = blockIdx.x;
  int per_xcd = (nb * 256) >> 3;
  int r = (blk & 7) * per_xcd + (blk >> 3);
  int bL = r >> 8;
  int rem = r & 255;
  int y = rem >> 1, h = rem & 1;
  int x0 = h * 64 - 12;                      // E col xl <-> global x = x0+xl
  const float* Sb = SAT + (size_t)bL * 96 * 17028;

  int t = threadIdx.x;
  int lane = t & 63, wv = t >> 6;            // 8 waves
  int lr = lane & 15, quad = lane >> 4;
  int px64 = t & 63;                         // build pixel (local)
  int pxg = h * 64 + px64;                   // global pixel

  f32x4 acc[4][4];
#pragma unroll
  for (int io = 0; io < 4; ++io)
#pragma unroll
    for (int ip = 0; ip < 4; ++ip) acc[io][ip] = (f32x4){0.f, 0.f, 0.f, 0.f};

  // ---- eload/ewrite: 96 ch x 23 float4 granules = 2208 tasks; 3 chunks of
  //      1024 (2 slots each; chunk 2048 has 160 live). T14 split. ----
  float4 ea[2], eb[2];

  auto eload = [&](int jr, int base) {
    int y1 = ((y - jr < 0) ? 0 : (y - jr)) * 132;
    int y2 = (((y + jr > 127) ? 127 : (y + jr)) + 1) * 132;
#pragma unroll
    for (int k = 0; k < 2; ++k) {
      int idx = base + t + (k << 9);
      if (idx < 2208) {
        int chn = idx / 23;
        int g = idx - chn * 23;
        int xb = x0 + (g << 2);
        xb = xb < 0 ? 0 : (xb > 128 ? 128 : xb);   // clamped cols never read
        const float* p = Sb + (size_t)chn * 17028 + xb;
        ea[k] = *(const float4*)(p + y2);
        eb[k] = *(const float4*)(p + y1);
      }
    }
  };

  auto ewrite = [&](int base) {
#pragma unroll
    for (int k = 0; k < 2; ++k) {
      int idx = base + t + (k << 9);
      if (idx < 2208) {
        int chn = idx / 23;
        int g = idx - chn * 23;
        float4 d;
        d.x = ea[k].x - eb[k].x; d.y = ea[k].y - eb[k].y;
        d.z = ea[k].z - eb[k].z; d.w = ea[k].w - eb[k].w;
        *(float4*)(E + chn * 92 + (g << 2)) = d;
      }
    }
  };

  // build As[px][ch] for ring jr from E (wave wv owns 12 channels).
  auto build = [&](int jr) {
    int gx2 = ((pxg + jr > 127) ? 127 : (pxg + jr)) + 1;
    int gx1 = (pxg - jr < 0) ? 0 : (pxg - jr);
    int xl2 = gx2 - x0, xl1 = gx1 - x0;
#pragma unroll
    for (int k = 0; k < 3; ++k) {
      int c = wv * 12 + (k << 2);
      const float* Ec = E + c * 92;
      union { bf16x4 v; __hip_bfloat16 hh[4]; } pk;
#pragma unroll
      for (int i = 0; i < 4; ++i)
        pk.hh[i] = __float2bfloat16(Ec[i * 92 + xl2] - Ec[i * 92 + xl1]);
      *(bf16x4*)(As + px64 * 104 + c) = pk.v;
    }
  };

  // one K-sub-phase: 4 V-frags (global) x 4 As-frags (LDS) -> 16 MFMA
  auto mfma_sub = [&](int j, int sub) {
    bf16x8 av[4], bs[4];
#pragma unroll
    for (int io = 0; io < 4; ++io)
      av[io] = *(const bf16x8*)(V + (size_t)(wv * 64 + io * 16 + lr) * 1248
                                + j * 96 + sub * 32 + quad * 8);
#pragma unroll
    for (int ip = 0; ip < 4; ++ip)
      bs[ip] = *(const bf16x8*)(As + (ip * 16 + lr) * 104 + sub * 32 + quad * 8);
    __builtin_amdgcn_s_setprio(1);
#pragma unroll
    for (int io = 0; io < 4; ++io)
#pragma unroll
      for (int ip = 0; ip < 4; ++ip)
        acc[io][ip] = __builtin_amdgcn_mfma_f32_16x16x32_bf16(
            av[io], bs[ip], acc[io][ip], 0, 0, 0);
    __builtin_amdgcn_s_setprio(0);
  };

  // ---- prologue: E <- ring0; build As(0) ----
  eload(0, 0); ewrite(0);
  eload(0, 1024); ewrite(1024);
  eload(0, 2048); ewrite(2048);
  __syncthreads();
  build(0);
  __syncthreads();

  // ---- main loop: P1 {mfma(j) + stage E<-j+1}; bar; P2 {build(j+1)}; bar ----
  for (int j = 0; j < 13; ++j) {
    bool pf = (j < 12);
    if (pf) eload(j + 1, 0);
    mfma_sub(j, 0);
    if (pf) { ewrite(0); eload(j + 1, 1024); }
    mfma_sub(j, 1);
    if (pf) { ewrite(1024); eload(j + 1, 2048); }
    mfma_sub(j, 2);
    if (pf) ewrite(2048);
    __syncthreads();
    if (pf) {
      build(j + 1);
      __syncthreads();
    }
  }

  // ---- epilogue A: bias+relu -> Yst[64 px][520 o1] bf16 (b64 writes) ----
  __hip_bfloat16* Yst = (__hip_bfloat16*)smem;   // 64*520*2 = 66560 B
#pragma unroll
  for (int io = 0; io < 4; ++io) {
    int o1b = wv * 64 + io * 16 + quad * 4;
    float4 bias = *(const float4*)(b1e + o1b);
#pragma unroll
    for (int ip = 0; ip < 4; ++ip) {
      int pxx = ip * 16 + lr;
      f32x4 a = acc[io][ip];
      float z0 = a[0] + bias.x; z0 = z0 > 0.f ? z0 : 0.f;
      float z1 = a[1] + bias.y; z1 = z1 > 0.f ? z1 : 0.f;
      float z2 = a[2] + bias.z; z2 = z2 > 0.f ? z2 : 0.f;
      float z3 = a[3] + bias.w; z3 = z3 > 0.f ? z3 : 0.f;
      union { bf16x4 v; __hip_bfloat16 hh[4]; } pk;
      pk.hh[0] = __float2bfloat16(z0); pk.hh[1] = __float2bfloat16(z1);
      pk.hh[2] = __float2bfloat16(z2); pk.hh[3] = __float2bfloat16(z3);
      *(bf16x4*)(Yst + pxx * 520 + o1b) = pk.v;
    }
  }
  __syncthreads();

  // ---- epilogue B: out[96 o2][64 px] = W2e[96][512] x Yst^T.
  //      wave = (o2-half of 48, px-quarter of 16): 3 o2-tiles each. ----
  int og = wv >> 2;          // 0,1
  int pg = wv & 3;           // 0..3
  f32x4 acc2[3];
#pragma unroll
  for (int im = 0; im < 3; ++im) acc2[im] = (f32x4){0.f, 0.f, 0.f, 0.f};

  for (int k2 = 0; k2 < 512; k2 += 32) {
    bf16x8 b2f = *(const bf16x8*)(Yst + (pg * 16 + lr) * 520 + k2 + quad * 8);
#pragma unroll
    for (int im = 0; im < 3; ++im) {
      bf16x8 a2f = *(const bf16x8*)(W2e + (size_t)(og * 48 + im * 16 + lr) * 512
                                    + k2 + quad * 8);
      acc2[im] = __builtin_amdgcn_mfma_f32_16x16x32_bf16(a2f, b2f, acc2[im], 0, 0, 0);
    }
  }

  size_t obase = ((size_t)(b0 + bL) * 96) * 16384 + (size_t)y * 128
                 + h * 64 + pg * 16 + lr;
#pragma unroll
  for (int im = 0; im < 3; ++im) {
#pragma unroll
    for (int rr = 0; rr < 4; ++rr) {
      int o2 = og * 48 + im * 16 + quad * 4 + rr;
      out[obase + (size_t)o2 * 16384] = acc2[im][rr] + b2e[o2];
    }
  }
}

// ---------------------------------------------------------------------------
extern "C" void kernel_launch(void* const* d_in, const int* in_sizes, int n_in,
                              void* d_out, int out_size, void* d_ws, size_t ws_size,
                              hipStream_t stream)
{
  const float* x   = (const float*)d_in[0];
  const float* g1  = (const float*)d_in[1];
  const float* be1 = (const float*)d_in[2];
  const float* mu1 = (const float*)d_in[3];
  const float* va1 = (const float*)d_in[4];
  const float* W1  = (const float*)d_in[5];
  const float* cb1 = (const float*)d_in[6];
  const float* g2  = (const float*)d_in[7];
  const float* be2 = (const float*)d_in[8];
  const float* mu2 = (const float*)d_in[9];
  const float* va2 = (const float*)d_in[10];
  const float* W2  = (const float*)d_in[11];
  const float* cb2 = (const float*)d_in[12];
  float* out = (float*)d_out;

  hipFuncSetAttribute((const void*)fused5_kernel,
                      hipFuncAttributeMaxDynamicSharedMemorySize, 66560);

  char* w = (char*)d_ws;
  __hip_bfloat16* V   = (__hip_bfloat16*)w; w += (size_t)512 * 1248 * 2;
  __hip_bfloat16* W2e = (__hip_bfloat16*)w; w += (size_t)96 * 512 * 2;
  float* b1e = (float*)w; w += 2048;
  float* b2e = (float*)w; w += 512;
  size_t fixed = (size_t)(w - (char*)d_ws);

  const size_t satB = (size_t)96 * 17028 * 4;     // per-batch SAT bytes
  int nb = (ws_size >= fixed + 4 * satB + 4096) ? 4 : 1;

  float* SAT = (float*)w;

  if (nb == 4) {
    prepsat_kernel<<<992, 512, 0, stream>>>(W1, cb1, g1, be1, mu1, va1,
                                            W2, cb2, g2, be2, mu2, va2,
                                            x, V, b1e, W2e, b2e, SAT, 384);
    fused5_kernel<<<1024, 512, 66560, stream>>>(SAT, V, b1e, W2e, b2e, out, 4, 0);
  } else {
    prepsat_kernel<<<608, 512, 0, stream>>>(W1, cb1, g1, be1, mu1, va1,
                                            W2, cb2, g2, be2, mu2, va2,
                                            x, V, b1e, W2e, b2e, SAT, 0);
    for (int b0 = 0; b0 < 4; ++b0) {
      satonly_kernel<<<96, 512, 0, stream>>>(x + (size_t)b0 * 96 * 16384, SAT);
      fused5_kernel<<<256, 512, 66560, stream>>>(SAT, V, b1e, W2e, b2e, out, 1, b0);
    }
  }
}

// Round 8
// 283.362 us; speedup vs baseline: 1.4070x; 1.1865x over previous
//
#include <hip/hip_runtime.h>
#include <hip/hip_bf16.h>
#include <cstdint>

typedef __attribute__((ext_vector_type(8))) short bf16x8;   // 8 bf16 (4 VGPRs)
typedef __attribute__((ext_vector_type(4))) short bf16x4;   // 4 bf16 (8 B)
typedef __attribute__((ext_vector_type(4))) float f32x4;    // MFMA C/D

#define BN_EPS 1e-5f

// ---------------------------------------------------------------------------
// sat plane (512 threads): exclusive SAT [129][132] per (b,c) plane.
// Cols 129..131 zeroed (eload granule at x=128 reads them).
// ---------------------------------------------------------------------------
__device__ __forceinline__ void sat_plane(const float* __restrict__ xp,
                                          float* __restrict__ Sg, int t)
{
  __shared__ float tile[16384];
  __shared__ float csA[512];
  __shared__ float csB[512];

  for (int i4 = t; i4 < 4096; i4 += 512) {
    int r = i4 >> 5;
    int g = i4 & 31;
    float4 v = *(const float4*)(xp + (size_t)r * 128 + g * 4);
    *(float4*)(tile + r * 128 + ((g ^ (r & 31)) << 2)) = v;
  }
  __syncthreads();

  int r = t & 127, ch = t >> 7;
  {
    float carry = 0.f;
#pragma unroll
    for (int g8 = 0; g8 < 8; ++g8) {
      int g = ch * 8 + g8;
      float* p = tile + r * 128 + ((g ^ (r & 31)) << 2);
      float4 v = *(float4*)p;
      float s0 = carry + v.x, s1 = s0 + v.y, s2 = s1 + v.z, s3 = s2 + v.w;
      float4 o; o.x = s0; o.y = s1; o.z = s2; o.w = s3;
      *(float4*)p = o;
      carry = s3;
    }
    csA[r * 4 + ch] = carry;
  }
  __syncthreads();
  if (ch > 0) {
    float offs = csA[r * 4 + 0];
    if (ch > 1) offs += csA[r * 4 + 1];
    if (ch > 2) offs += csA[r * 4 + 2];
#pragma unroll
    for (int g8 = 0; g8 < 8; ++g8) {
      int g = ch * 8 + g8;
      float* p = tile + r * 128 + ((g ^ (r & 31)) << 2);
      float4 v = *(float4*)p;
      v.x += offs; v.y += offs; v.z += offs; v.w += offs;
      *(float4*)p = v;
    }
  }
  __syncthreads();

  int xcol = t & 127, rc = t >> 7;
  int gc = xcol >> 2, wc = xcol & 3;
  float regs[32];
  {
    float run = 0.f;
#pragma unroll
    for (int r8 = 0; r8 < 32; ++r8) {
      int rr = rc * 32 + r8;
      run += tile[rr * 128 + ((gc ^ (rr & 31)) << 2) + wc];
      regs[r8] = run;
    }
    csB[xcol * 4 + rc] = run;
  }
  if (t < 132) Sg[t] = 0.f;                 // row 0, cols 0..131
  if (t < 128) Sg[(t + 1) * 132] = 0.f;     // col 0
  if (t < 128) {                            // pad cols 129..131
    float* rp = Sg + (size_t)(t + 1) * 132;
    rp[129] = 0.f; rp[130] = 0.f; rp[131] = 0.f;
  }
  __syncthreads();

  float offs = 0.f;
  if (rc > 0) offs += csB[xcol * 4 + 0];
  if (rc > 1) offs += csB[xcol * 4 + 1];
  if (rc > 2) offs += csB[xcol * 4 + 2];
#pragma unroll
  for (int r8 = 0; r8 < 32; ++r8) {
    int rr = rc * 32 + r8;
    Sg[(rr + 1) * 132 + xcol + 1] = regs[r8] + offs;
  }
}

// ---------------------------------------------------------------------------
// prepsat: blocks [0,512) prep1; [512,608) prep2; [608,608+nplanes) sat.
// ---------------------------------------------------------------------------
__global__ __launch_bounds__(512) void prepsat_kernel(
    const float* __restrict__ W1, const float* __restrict__ cb1,
    const float* __restrict__ g1, const float* __restrict__ be1,
    const float* __restrict__ mu1, const float* __restrict__ va1,
    const float* __restrict__ W2, const float* __restrict__ cb2,
    const float* __restrict__ g2, const float* __restrict__ be2,
    const float* __restrict__ mu2, const float* __restrict__ va2,
    const float* __restrict__ x,
    __hip_bfloat16* __restrict__ V, float* __restrict__ b1e,
    __hip_bfloat16* __restrict__ W2e, float* __restrict__ b2e,
    float* __restrict__ SAT, int nplanes)
{
  int blk = blockIdx.x;
  int t = threadIdx.x;
  if (blk < 512) {
    __shared__ float red[8];
    int o = blk;
    const float* wrow = W1 + (size_t)o * 1248;
    float acc = 0.f;
    for (int i = t; i < 1248; i += 512) {
      float s = g1[i] * rsqrtf(va1[i] + BN_EPS);
      float w = wrow[i];
      acc += w * (be1[i] - mu1[i] * s);
      float g = w * s;
      float gn = 0.f;
      if (i < 1152) {
        float sn = g1[i + 96] * rsqrtf(va1[i + 96] + BN_EPS);
        gn = wrow[i + 96] * sn;
      }
      V[(size_t)o * 1248 + i] = __float2bfloat16(g - gn);
    }
    for (int d = 32; d > 0; d >>= 1) acc += __shfl_down(acc, d);
    int lane = t & 63, wvv = t >> 6;
    if (lane == 0) red[wvv] = acc;
    __syncthreads();
    if (t == 0) {
      float s = cb1[o];
#pragma unroll
      for (int i = 0; i < 8; ++i) s += red[i];
      b1e[o] = s;
    }
  } else if (blk < 608) {
    __shared__ float red2[8];
    int o = blk - 512;
    const float* wrow = W2 + (size_t)o * 512;
    float acc;
    {
      int j = t;
      float s = g2[j] * rsqrtf(va2[j] + BN_EPS);
      float wv = wrow[j];
      acc = wv * (be2[j] - mu2[j] * s);
      W2e[(size_t)o * 512 + j] = __float2bfloat16(wv * s);
    }
    for (int d = 32; d > 0; d >>= 1) acc += __shfl_down(acc, d);
    int lane = t & 63, wvv = t >> 6;
    if (lane == 0) red2[wvv] = acc;
    __syncthreads();
    if (t == 0) {
      float s = cb2[o];
#pragma unroll
      for (int i = 0; i < 8; ++i) s += red2[i];
      b2e[o] = s;
    }
  } else {
    int plane = blk - 608;
    if (plane < nplanes)
      sat_plane(x + (size_t)plane * 16384, SAT + (size_t)plane * 17028, t);
  }
}

__global__ __launch_bounds__(512) void satonly_kernel(
    const float* __restrict__ x, float* __restrict__ SAT)
{
  sat_plane(x + (size_t)blockIdx.x * 16384,
            SAT + (size_t)blockIdx.x * 17028, threadIdx.x);
}

// ---------------------------------------------------------------------------
// fused v11 = R2's verified v6 data path (E[c][x] f32, scalar build reads,
// 3-reg T14 staging) with exactly two changes its counters justify:
//  1. As double-buffered (stride 104 -> 108 bf16: 54 words, gcd(54,32)=2 ->
//     16-bank spread on MFMA B-reads and build writes; was 8-way at 52w)
//     -> ONE barrier per ring; build(j+1) interleaved between MFMA subs,
//     ordered so staging regs (ea/eb) are DEAD during build (R5's spill fix).
//  2. Nothing else. 512 thr / 8 waves / (512,2) = 256 regs/wave, acc[8][4].
// Phase j: eload(j+2,h0); mfma0(Asr); ewrite(h0); build_k(j+1,{0,1});
//          eload(h1); mfma1; ewrite(h1); build_k(j+1,{2}); mfma2; barrier.
// Buffers: E parity (j+2)&1 = j&1 (E(j) dead), As parity (j+1)&1 (As(j-1)
// dead) -> all hazards lag-1 across the single barrier.
// LDS: E0,E1 50688 ea + As0,As1 27648 ea = 156672; Yst[128][520] = 133120
// aliases for epilogues. 1 block/CU (as R2).
// ---------------------------------------------------------------------------
__global__ __launch_bounds__(512, 2) void fused6_kernel(
    const float* __restrict__ SAT, const __hip_bfloat16* __restrict__ V,
    const float* __restrict__ b1e, const __hip_bfloat16* __restrict__ W2e,
    const float* __restrict__ b2e, float* __restrict__ out, int nb, int b0)
{
  extern __shared__ __align__(16) char smem[];
  float* E0 = (float*)smem;                                  // 96*132 fp32
  float* E1 = (float*)(smem + 50688);
  __hip_bfloat16* As0 = (__hip_bfloat16*)(smem + 101376);    // [128][108]
  __hip_bfloat16* As1 = (__hip_bfloat16*)(smem + 129024);

  int blk = blockIdx.x;
  int rows_per_xcd = (nb * 128) >> 3;
  int r = (blk & 7) * rows_per_xcd + (blk >> 3);
  int bL = r >> 7, y = r & 127;

  int t = threadIdx.x;
  int lane = t & 63, wv = t >> 6;              // 8 waves
  int wo = wv >> 1, wp = wv & 1;               // o1-slab (128), px-half (64)
  int lr = lane & 15, quad = lane >> 4;
  int px = t & 127;                            // build pixel
  int bg = t >> 7;                             // build granule base 0..3

  const float* Sb = SAT + (size_t)bL * 96 * 17028;

  f32x4 acc[8][4];
#pragma unroll
  for (int io = 0; io < 8; ++io)
#pragma unroll
    for (int ip = 0; ip < 4; ++ip) acc[io][ip] = (f32x4){0.f, 0.f, 0.f, 0.f};

  // ---- efill staging registers (T14 split: load early, write late) ----
  float4 ea[3], eb[3];
  float ta = 0.f, tb = 0.f;

  auto eload = [&](int jr, int h) {
    int y1 = ((y - jr < 0) ? 0 : (y - jr)) * 132;
    int y2 = (((y + jr > 127) ? 127 : (y + jr)) + 1) * 132;
#pragma unroll
    for (int k = 0; k < 3; ++k) {
      int idx = t + 512 * (h * 3 + k);
      int cl = idx >> 5, ck = idx & 31;
      const float* bp = Sb + (size_t)cl * 17028 + ck * 4;
      ea[k] = *(const float4*)(bp + y2);
      eb[k] = *(const float4*)(bp + y1);
    }
    if (h == 1 && t < 96) {   // x = 128 column tail
      const float* bp = Sb + (size_t)t * 17028 + 128;
      ta = bp[y2];
      tb = bp[y1];
    }
  };

  auto ewrite = [&](float* E, int h) {
#pragma unroll
    for (int k = 0; k < 3; ++k) {
      int idx = t + 512 * (h * 3 + k);
      int cl = idx >> 5, ck = idx & 31;
      float4 d;
      d.x = ea[k].x - eb[k].x; d.y = ea[k].y - eb[k].y;
      d.z = ea[k].z - eb[k].z; d.w = ea[k].w - eb[k].w;
      *(float4*)(E + cl * 132 + ck * 4) = d;
    }
    if (h == 1 && t < 96) E[t * 132 + 128] = ta - tb;
  };

  // build As granules [k0,k1) for ring jr from E (thread: granules bg+4k)
  auto build_k = [&](const float* E, __hip_bfloat16* As, int jr, int k0, int k1) {
    int x1 = (px - jr < 0) ? 0 : (px - jr);
    int x2 = ((px + jr > 127) ? 127 : (px + jr)) + 1;
#pragma unroll
    for (int k = k0; k < k1; ++k) {
      int g = bg + 4 * k;
      const float* Eb = E + g * 8 * 132;
      union { bf16x8 v; __hip_bfloat16 h8[8]; } pk;
#pragma unroll
      for (int i = 0; i < 8; ++i)
        pk.h8[i] = __float2bfloat16(Eb[i * 132 + x2] - Eb[i * 132 + x1]);
      *(bf16x8*)(As + px * 108 + g * 8) = pk.v;
    }
  };

  // one K-sub-phase: 8 V-frags (global) x 4 As-frags (LDS) -> 32 MFMA
  auto mfma_sub = [&](int j, int sub, const __hip_bfloat16* As) {
    bf16x8 av[8], bs[4];
#pragma unroll
    for (int io = 0; io < 8; ++io)
      av[io] = *(const bf16x8*)(V + (size_t)(wo * 128 + io * 16 + lr) * 1248
                                + j * 96 + sub * 32 + quad * 8);
#pragma unroll
    for (int ip = 0; ip < 4; ++ip)
      bs[ip] = *(const bf16x8*)(As + (wp * 64 + ip * 16 + lr) * 108 + sub * 32 + quad * 8);
    __builtin_amdgcn_s_setprio(1);
#pragma unroll
    for (int io = 0; io < 8; ++io)
#pragma unroll
      for (int ip = 0; ip < 4; ++ip)
        acc[io][ip] = __builtin_amdgcn_mfma_f32_16x16x32_bf16(av[io], bs[ip], acc[io][ip], 0, 0, 0);
    __builtin_amdgcn_s_setprio(0);
  };

  // ---- prologue: E0 <- ring0; then E1 <- ring1 while As0 <- ring0 ----
  eload(0, 0); ewrite(E0, 0); eload(0, 1); ewrite(E0, 1);
  __syncthreads();
  eload(1, 0); ewrite(E1, 0);
  build_k(E0, As0, 0, 0, 2);
  eload(1, 1); ewrite(E1, 1);
  build_k(E0, As0, 0, 2, 3);
  __syncthreads();

  // ---- main loop: ONE barrier per ring ----
  for (int j = 0; j < 13; ++j) {
    float* Ew = (j & 1) ? E1 : E0;                     // ring j+2 target
    const float* Er = (j & 1) ? E0 : E1;               // ring j+1 source
    const __hip_bfloat16* Asr = (j & 1) ? As1 : As0;   // ring j
    __hip_bfloat16* Asw = (j & 1) ? As0 : As1;         // ring j+1
    bool pf = (j < 11), bd = (j < 12);
    if (pf) eload(j + 2, 0);
    mfma_sub(j, 0, Asr);
    if (pf) ewrite(Ew, 0);
    if (bd) build_k(Er, Asw, j + 1, 0, 2);    // staging regs dead here
    if (pf) eload(j + 2, 1);
    mfma_sub(j, 1, Asr);
    if (pf) ewrite(Ew, 1);
    if (bd) build_k(Er, Asw, j + 1, 2, 3);    // staging regs dead here
    mfma_sub(j, 2, Asr);
    __syncthreads();
  }

  // ---- epilogue A: bias+relu -> Yst[128 px][520 o1] bf16, b64 writes ----
  __hip_bfloat16* Yst = (__hip_bfloat16*)smem;   // 128*520*2 = 133120 B
#pragma unroll
  for (int io = 0; io < 8; ++io) {
    int o1b = wo * 128 + io * 16 + quad * 4;
    float4 bias = *(const float4*)(b1e + o1b);
#pragma unroll
    for (int ip = 0; ip < 4; ++ip) {
      int pxx = wp * 64 + ip * 16 + lr;
      f32x4 a = acc[io][ip];
      float z0 = a[0] + bias.x; z0 = z0 > 0.f ? z0 : 0.f;
      float z1 = a[1] + bias.y; z1 = z1 > 0.f ? z1 : 0.f;
      float z2 = a[2] + bias.z; z2 = z2 > 0.f ? z2 : 0.f;
      float z3 = a[3] + bias.w; z3 = z3 > 0.f ? z3 : 0.f;
      union { bf16x4 v; __hip_bfloat16 hh[4]; } pk;
      pk.hh[0] = __float2bfloat16(z0); pk.hh[1] = __float2bfloat16(z1);
      pk.hh[2] = __float2bfloat16(z2); pk.hh[3] = __float2bfloat16(z3);
      *(bf16x4*)(Yst + pxx * 520 + o1b) = pk.v;
    }
  }
  __syncthreads();

  // ---- epilogue B: out[96 o2][128 px] = W2e[96][512] x Yst^T ----
  int og = wv >> 2;          // 0,1
  int pg = wv & 3;           // 0..3
  f32x4 acc2[3][2];
#pragma unroll
  for (int im = 0; im < 3; ++im)
#pragma unroll
    for (int tl = 0; tl < 2; ++tl) acc2[im][tl] = (f32x4){0.f, 0.f, 0.f, 0.f};

  for (int k2 = 0; k2 < 512; k2 += 32) {
    bf16x8 bfr2[2];
#pragma unroll
    for (int tl = 0; tl < 2; ++tl)
      bfr2[tl] = *(const bf16x8*)(Yst + (pg * 32 + tl * 16 + lr) * 520 + k2 + quad * 8);
#pragma unroll
    for (int im = 0; im < 3; ++im) {
      bf16x8 afr2 = *(const bf16x8*)(W2e + (size_t)(og * 48 + im * 16 + lr) * 512
                                     + k2 + quad * 8);
#pragma unroll
      for (int tl = 0; tl < 2; ++tl)
        acc2[im][tl] = __builtin_amdgcn_mfma_f32_16x16x32_bf16(afr2, bfr2[tl], acc2[im][tl], 0, 0, 0);
    }
  }

  size_t obase = ((size_t)(b0 + bL) * 96) * 16384 + (size_t)y * 128;
#pragma unroll
  for (int im = 0; im < 3; ++im) {
#pragma unroll
    for (int tl = 0; tl < 2; ++tl) {
      int pxx = pg * 32 + tl * 16 + lr;
#pragma unroll
      for (int rr = 0; rr < 4; ++rr) {
        int o2 = og * 48 + im * 16 + quad * 4 + rr;
        out[obase + (size_t)o2 * 16384 + pxx] = acc2[im][tl][rr] + b2e[o2];
      }
    }
  }
}

// ---------------------------------------------------------------------------
extern "C" void kernel_launch(void* const* d_in, const int* in_sizes, int n_in,
                              void* d_out, int out_size, void* d_ws, size_t ws_size,
                              hipStream_t stream)
{
  const float* x   = (const float*)d_in[0];
  const float* g1  = (const float*)d_in[1];
  const float* be1 = (const float*)d_in[2];
  const float* mu1 = (const float*)d_in[3];
  const float* va1 = (const float*)d_in[4];
  const float* W1  = (const float*)d_in[5];
  const float* cb1 = (const float*)d_in[6];
  const float* g2  = (const float*)d_in[7];
  const float* be2 = (const float*)d_in[8];
  const float* mu2 = (const float*)d_in[9];
  const float* va2 = (const float*)d_in[10];
  const float* W2  = (const float*)d_in[11];
  const float* cb2 = (const float*)d_in[12];
  float* out = (float*)d_out;

  hipFuncSetAttribute((const void*)fused6_kernel,
                      hipFuncAttributeMaxDynamicSharedMemorySize, 156672);

  char* w = (char*)d_ws;
  __hip_bfloat16* V   = (__hip_bfloat16*)w; w += (size_t)512 * 1248 * 2;
  __hip_bfloat16* W2e = (__hip_bfloat16*)w; w += (size_t)96 * 512 * 2;
  float* b1e = (float*)w; w += 2048;
  float* b2e = (float*)w; w += 512;
  size_t fixed = (size_t)(w - (char*)d_ws);

  const size_t satB = (size_t)96 * 17028 * 4;     // per-batch SAT bytes
  int nb = (ws_size >= fixed + 4 * satB + 4096) ? 4 : 1;

  float* SAT = (float*)w;

  if (nb == 4) {
    prepsat_kernel<<<992, 512, 0, stream>>>(W1, cb1, g1, be1, mu1, va1,
                                            W2, cb2, g2, be2, mu2, va2,
                                            x, V, b1e, W2e, b2e, SAT, 384);
    fused6_kernel<<<512, 512, 156672, stream>>>(SAT, V, b1e, W2e, b2e, out, 4, 0);
  } else {
    prepsat_kernel<<<608, 512, 0, stream>>>(W1, cb1, g1, be1, mu1, va1,
                                            W2, cb2, g2, be2, mu2, va2,
                                            x, V, b1e, W2e, b2e, SAT, 0);
    for (int b0 = 0; b0 < 4; ++b0) {
      satonly_kernel<<<96, 512, 0, stream>>>(x + (size_t)b0 * 96 * 16384, SAT);
      fused6_kernel<<<128, 512, 156672, stream>>>(SAT, V, b1e, W2e, b2e, out, 1, b0);
    }
  }
}